// Round 7
// baseline (1049.666 us; speedup 1.0000x reference)
//
#include <hip/hip_runtime.h>
#include <hip/hip_bf16.h>
#include <stdint.h>

#define AS1 __attribute__((address_space(1)))
#define AS3 __attribute__((address_space(3)))

typedef _Float16 f16x8 __attribute__((ext_vector_type(8)));
typedef _Float16 f16x2 __attribute__((ext_vector_type(2)));
typedef float f32x16 __attribute__((ext_vector_type(16)));

union AF { f16x8 v; f16x2 p[4]; };

__device__ __forceinline__ ushort f2h(float f){
  union { _Float16 h; ushort u; } cv; cv.h = (_Float16)f; return cv.u;
}
__device__ __forceinline__ _Float16 u2h(ushort u){
  union { _Float16 h; ushort u; } cv; cv.u = u; return cv.h;
}

// ---------------------------------------------------------------------------
// Pack W: fp32 [A=128][N=64][M=64][O=64] -> fp16 fragment-ordered stream.
// ws fp16 element index:
//   (n*64+m)*8192 + (s*4+wn)*512 + (g*32+la)*8 + i
//     = fp16( W[a=wn*32+la][n][m][o=s*16+g*8+i] )
// One block per (n,m): coalesced global read, XOR-swizzled LDS transpose,
// coalesced 16B chunk writes (1024 chunks -> j<4). Verified rounds 5-6.
// ---------------------------------------------------------------------------
__global__ __launch_bounds__(256) void pack_w_kernel(const float* __restrict__ W,
                                                     ushort* __restrict__ wsp){
  __shared__ ushort lds[128 * 64];    // lds[a*64 + (o ^ ((a&7)<<3))] = h(W[a][o])
  const int nm  = blockIdx.x;         // n*64 + m
  const int n   = nm >> 6;
  const int m   = nm & 63;
  const int tid = threadIdx.x;
  const float* src = W + ((size_t)n << 12) + ((size_t)m << 6);  // + (a<<18) + o

  #pragma unroll
  for (int j = 0; j < 32; ++j){
    const int e = tid + 256 * j;      // a = e>>6, o = e&63 (=lane)
    const int a = e >> 6, o = e & 63;
    const float v = src[((size_t)a << 18) + o];
    lds[a*64 + (o ^ ((a & 7) << 3))] = f2h(v);
  }
  __syncthreads();

  ushort* dst = wsp + (size_t)nm * 8192;
  #pragma unroll
  for (int j = 0; j < 4; ++j){        // 1024 chunks of 8 halfwords
    const int c  = tid + 256 * j;
    const int f  = c >> 6;            // s*4 + wn
    const int q  = c & 63;            // g*32 + la
    const int wn = f & 3, s = f >> 2;
    const int g  = q >> 5, la = q & 31;
    const int a  = wn*32 + la;
    const int o0 = s*16 + g*8;
    *(uint4*)(dst + (size_t)c * 8) =
        *(const uint4*)(lds + a*64 + (o0 ^ ((a & 7) << 3)));
  }
}

// ---------------------------------------------------------------------------
// out[b,a] = sum_{n,m,o} x1[b,n] x2[b,m] x3[b,o] W[a,n,m,o] + bias[a]
// fp16 datapath, A-frag = h(x1*x2)*h(x3) via v_pk_mul_f16. BM=512, 8 waves x
// (64 rows x 128 cols).
// ROUND 7: barrier window = 4 k-blocks (one m x 4 n) = 64KB W, double-buffered
// (128KB LDS). 128 windows x 128 MFMAs/wave -> per-window fixed cost (barrier
// skew + LDS ramp, measured ~950cyc/iter in r5/r6) amortized 8x. Single
// vmcnt(0)+s_barrier per window (loads issued a full ~8000-cyc window ahead,
// drain is stall-free -> no counted-vmcnt bookkeeping needed).
// x2: 2 scattered global fp32 loads/wave/window prefetched 1 window ahead
// into regs (x2 is 4MB, L2/L3-resident). x1: 8KB LDS tile [n][row].
// 256 blocks = 1/CU, splitK=8, nsplit = bid&7 = XCD (L2-lockstep, FETCH 74MB).
// mfma_f32_32x32x16_f16; D layout: col=lane&31, row=(r&3)+8*(r>>2)+4*(lane>>5).
// ---------------------------------------------------------------------------
__global__ __launch_bounds__(512, 2) void trilinear_gemm_kernel(
    const float* __restrict__ x1g, const float* __restrict__ x2g,
    const float* __restrict__ x3g, const ushort* __restrict__ wsp,
    const float* __restrict__ biasg, float* __restrict__ outg){

  __shared__ __align__(16) char Bbuf[2][4][16384];  // 128 KB: [buf][nt][slab]
  __shared__ ushort x1s[8 * 512];                   //   8 KB: [n][row]

  const int tid  = threadIdx.x;
  const int wave = tid >> 6;
  const int lane = tid & 63;
  const int la   = lane & 31;
  const int lg   = lane >> 5;

  const int bid    = blockIdx.x;
  const int nsplit = bid & 7;       // == XCD id under round-robin dispatch
  const int row0   = (bid >> 3) * 512;
  const int n0     = nsplit * 8;

  // ---- stage x1 transposed: x1s[nc][row]
  #pragma unroll
  for (int j = 0; j < 8; ++j)
    x1s[j*512 + tid] = f2h(x1g[(size_t)(row0 + tid)*64 + n0 + j]);

  // ---- this lane's two x3 rows -> fp16 pairs (2 x 16 VGPRs)
  f16x2 x3h[2][16];
  #pragma unroll
  for (int g = 0; g < 2; ++g){
    const int arow = row0 + wave*64 + g*32 + la;
    #pragma unroll
    for (int s = 0; s < 4; ++s){
      const float4 p0 = *(const float4*)(x3g + (size_t)arow*64 + s*16 + lg*8);
      const float4 p1 = *(const float4*)(x3g + (size_t)arow*64 + s*16 + lg*8 + 4);
      x3h[g][s*4+0] = f16x2{(_Float16)p0.x, (_Float16)p0.y};
      x3h[g][s*4+1] = f16x2{(_Float16)p0.z, (_Float16)p0.w};
      x3h[g][s*4+2] = f16x2{(_Float16)p1.x, (_Float16)p1.y};
      x3h[g][s*4+3] = f16x2{(_Float16)p1.z, (_Float16)p1.w};
    }
  }

  f32x16 acc[2][4];
  #pragma unroll
  for (int g = 0; g < 2; ++g)
    #pragma unroll
    for (int wn = 0; wn < 4; ++wn) acc[g][wn] = 0.f;

  // ---- x2 scatter prefetch for window 0 (mt = 0)
  const size_t x2off0 = (size_t)(row0 + wave*64 + la) * 64;
  const size_t x2off1 = (size_t)(row0 + wave*64 + 32 + la) * 64;
  float x2f0 = x2g[x2off0];
  float x2f1 = x2g[x2off1];

  // ---- W DMA for window 0 (mt=0, nh=0)
  #pragma unroll
  for (int nt = 0; nt < 4; ++nt){
    const size_t slab = (size_t)((n0 + nt) * 64) * 16384;   // bytes; mt=0
    const char* sp = (const char*)wsp + slab + wave*2048 + lane*16;
    char* dp = &Bbuf[0][nt][0] + wave*2048;
    __builtin_amdgcn_global_load_lds((const AS1 uint32_t*)sp,        (AS3 uint32_t*)dp,        16, 0, 0);
    __builtin_amdgcn_global_load_lds((const AS1 uint32_t*)(sp+1024), (AS3 uint32_t*)(dp+1024), 16, 0, 0);
  }
  __syncthreads();   // full drain: x1s stores + window-0 DMA + x2 prefetch

  const int rl0 = wave*64 + la;
  const int rl1 = rl0 + 32;

  for (int wi = 0; wi < 128; ++wi){    // 64 mt x 2 n-halves
    // top of window: own DMA + x2 loads were issued ~1 window (~8000cyc) ago
    asm volatile("s_waitcnt vmcnt(0)\n\ts_barrier" ::: "memory");

    const int nh = wi & 1;
    // ---- h for this window from preloaded x2 regs + x1 LDS
    const _Float16 xa = (_Float16)x2f0, xb = (_Float16)x2f1;
    f16x2 hs[4][2];
    #pragma unroll
    for (int nt = 0; nt < 4; ++nt){
      const _Float16 v0 = u2h(x1s[(nh*4 + nt)*512 + rl0]) * xa;
      const _Float16 v1 = u2h(x1s[(nh*4 + nt)*512 + rl1]) * xb;
      hs[nt][0] = f16x2{v0, v0};
      hs[nt][1] = f16x2{v1, v1};
    }

    // ---- issue DMA + x2 prefetch for window wi+1 (post-barrier: WAR-safe)
    const int wnx = (wi + 1) & 127;
    const int mtn = wnx >> 1, nhn = wnx & 1;
    #pragma unroll
    for (int nt = 0; nt < 4; ++nt){
      const size_t slab = (size_t)((n0 + nhn*4 + nt)*64 + mtn) * 16384;
      const char* sp = (const char*)wsp + slab + wave*2048 + lane*16;
      char* dp = &Bbuf[(wi + 1) & 1][nt][0] + wave*2048;
      __builtin_amdgcn_global_load_lds((const AS1 uint32_t*)sp,        (AS3 uint32_t*)dp,        16, 0, 0);
      __builtin_amdgcn_global_load_lds((const AS1 uint32_t*)(sp+1024), (AS3 uint32_t*)(dp+1024), 16, 0, 0);
    }
    x2f0 = x2g[x2off0 + mtn];
    x2f1 = x2g[x2off1 + mtn];

    // ---- compute: 4 nt x 4 s x (4 b128 + 8 pk_mul + 8 MFMA)
    const char* bw = &Bbuf[wi & 1][0][0] + (lane << 4);
    __builtin_amdgcn_s_setprio(1);
    #pragma unroll
    for (int nt = 0; nt < 4; ++nt){
      const char* bb = bw + nt*16384;
      #pragma unroll
      for (int s = 0; s < 4; ++s){
        AF a0, a1;
        #pragma unroll
        for (int jj = 0; jj < 4; ++jj){
          a0.p[jj] = hs[nt][0] * x3h[0][s*4 + jj];   // v_pk_mul_f16
          a1.p[jj] = hs[nt][1] * x3h[1][s*4 + jj];
        }
        #pragma unroll
        for (int wn = 0; wn < 4; ++wn){
          const f16x8 bf = *(const f16x8*)(bb + ((s*4 + wn) << 10));
          acc[0][wn] = __builtin_amdgcn_mfma_f32_32x32x16_f16(a0.v, bf, acc[0][wn], 0, 0, 0);
          acc[1][wn] = __builtin_amdgcn_mfma_f32_32x32x16_f16(a1.v, bf, acc[1][wn], 0, 0, 0);
        }
      }
    }
    __builtin_amdgcn_s_setprio(0);
  }

  // ---- epilogue: atomic accumulate split-K partials; split 0 carries bias
  #pragma unroll
  for (int g = 0; g < 2; ++g){
    #pragma unroll
    for (int wn = 0; wn < 4; ++wn){
      const int col = wn*32 + la;
      const float bv = (nsplit == 0) ? biasg[col] : 0.f;
      #pragma unroll
      for (int r = 0; r < 16; ++r){
        const int row = row0 + wave*64 + g*32 + (r & 3) + 8*(r >> 2) + 4*lg;
        atomicAdd(outg + (size_t)row*128 + col, acc[g][wn][r] + bv);
      }
    }
  }
}

// ---------------------------------------------------------------------------
extern "C" void kernel_launch(void* const* d_in, const int* in_sizes, int n_in,
                              void* d_out, int out_size, void* d_ws, size_t ws_size,
                              hipStream_t stream){
  const float* x1   = (const float*)d_in[0];
  const float* x2   = (const float*)d_in[1];
  const float* x3   = (const float*)d_in[2];
  const float* W    = (const float*)d_in[3];
  const float* bias = (const float*)d_in[4];
  float* out = (float*)d_out;

  // d_out is re-poisoned before every launch: zero it (split-K accumulates on top)
  hipMemsetAsync(d_out, 0, (size_t)16384 * 128 * sizeof(float), stream);

  // need 64 MB of scratch for the fp16-packed W
  if (ws_size < (size_t)64 * 1024 * 1024) return;

  ushort* wsp = (ushort*)d_ws;
  pack_w_kernel<<<4096, 256, 0, stream>>>(W, wsp);
  trilinear_gemm_kernel<<<256, 512, 0, stream>>>(x1, x2, x3, wsp, bias, out);
}